// Round 3
// baseline (272.571 us; speedup 1.0000x reference)
//
#include <hip/hip_runtime.h>

#define GIOU_GRID    2048
#define GIOU_THREADS 256
#define UNROLL       4

__device__ __forceinline__ float giou_loss(float4 p, float4 t) {
    float area_p = (p.z - p.x) * (p.w - p.y);
    float area_t = (t.z - t.x) * (t.w - t.y);

    float iw = fmaxf(fminf(p.z, t.z) - fmaxf(p.x, t.x), 0.0f);
    float ih = fmaxf(fminf(p.w, t.w) - fmaxf(p.y, t.y), 0.0f);
    float inter = iw * ih;
    float uni   = area_p + area_t - inter;

    float ew = fmaxf(p.z, t.z) - fminf(p.x, t.x);
    float eh = fmaxf(p.w, t.w) - fminf(p.y, t.y);
    float enclose = ew * eh;

    // 1 - giou = 2 - inter/union - union/enclose  (fast rcp: err ~1e-5 << 2.75e-2 threshold)
    return 2.0f - inter * __builtin_amdgcn_rcpf(uni)
                - uni   * __builtin_amdgcn_rcpf(enclose);
}

__global__ __launch_bounds__(GIOU_THREADS) void giou_partial_kernel(
        const float4* __restrict__ pred,
        const float4* __restrict__ targ,
        double* __restrict__ partials,
        int n) {
    // Contiguous per-block slice: block walks a ~1 MB window of each array
    // (streaming locality) instead of 8 MB grid-stride jumps.
    int per_block = (n + GIOU_GRID - 1) / GIOU_GRID;
    int start = blockIdx.x * per_block;
    int end   = min(n, start + per_block);

    float sum = 0.0f;
    int i = start + (int)threadIdx.x;

    // Main loop: force all 8 dwordx4 loads outstanding before any compute.
    for (; i + (UNROLL - 1) * GIOU_THREADS < end; i += UNROLL * GIOU_THREADS) {
        float4 p[UNROLL], t[UNROLL];
        #pragma unroll
        for (int u = 0; u < UNROLL; ++u) p[u] = pred[i + u * GIOU_THREADS];
        #pragma unroll
        for (int u = 0; u < UNROLL; ++u) t[u] = targ[i + u * GIOU_THREADS];
        // Pin the 8 loads before the compute phase: values must be live across
        // this barrier, so the compiler cannot re-serialize into load->use pairs.
        __builtin_amdgcn_sched_barrier(0);
        #pragma unroll
        for (int u = 0; u < UNROLL; ++u) sum += giou_loss(p[u], t[u]);
    }
    // remainder
    for (; i < end; i += GIOU_THREADS) sum += giou_loss(pred[i], targ[i]);

    // wave-64 butterfly reduction
    #pragma unroll
    for (int off = 32; off > 0; off >>= 1)
        sum += __shfl_down(sum, off, 64);

    __shared__ float wave_sums[GIOU_THREADS / 64];
    int lane = threadIdx.x & 63;
    int wave = threadIdx.x >> 6;
    if (lane == 0) wave_sums[wave] = sum;
    __syncthreads();

    if (threadIdx.x == 0) {
        double b = 0.0;
        #pragma unroll
        for (int w = 0; w < GIOU_THREADS / 64; ++w) b += (double)wave_sums[w];
        partials[blockIdx.x] = b;   // every block writes unconditionally -> no memset needed
    }
}

__global__ __launch_bounds__(GIOU_THREADS) void giou_final_kernel(
        const double* __restrict__ partials,
        float* __restrict__ out,
        int nblocks, int n) {
    double s = 0.0;
    for (int i = threadIdx.x; i < nblocks; i += blockDim.x)
        s += partials[i];

    #pragma unroll
    for (int off = 32; off > 0; off >>= 1)
        s += __shfl_down(s, off, 64);

    __shared__ double wave_sums[GIOU_THREADS / 64];
    int lane = threadIdx.x & 63;
    int wave = threadIdx.x >> 6;
    if (lane == 0) wave_sums[wave] = s;
    __syncthreads();

    if (threadIdx.x == 0) {
        double tot = 0.0;
        #pragma unroll
        for (int w = 0; w < GIOU_THREADS / 64; ++w) tot += wave_sums[w];
        out[0] = (float)(tot / (double)n);
    }
}

extern "C" void kernel_launch(void* const* d_in, const int* in_sizes, int n_in,
                              void* d_out, int out_size, void* d_ws, size_t ws_size,
                              hipStream_t stream) {
    const float4* pred = (const float4*)d_in[0];
    const float4* targ = (const float4*)d_in[1];
    float* out = (float*)d_out;
    double* partials = (double*)d_ws;   // GIOU_GRID doubles = 16 KB

    int n = in_sizes[0] / 4;            // number of boxes (flat count is n*4)

    giou_partial_kernel<<<GIOU_GRID, GIOU_THREADS, 0, stream>>>(pred, targ, partials, n);
    giou_final_kernel<<<1, GIOU_THREADS, 0, stream>>>(partials, out, GIOU_GRID, n);
}

// Round 4
// 248.441 us; speedup vs baseline: 1.0971x; 1.0971x over previous
//
#include <hip/hip_runtime.h>

#define GIOU_GRID    4096
#define GIOU_THREADS 256
#define UNROLL       4

typedef float v4f __attribute__((ext_vector_type(4)));

__device__ __forceinline__ float giou_loss(v4f p, v4f t) {
    float area_p = (p.z - p.x) * (p.w - p.y);
    float area_t = (t.z - t.x) * (t.w - t.y);

    float iw = fmaxf(fminf(p.z, t.z) - fmaxf(p.x, t.x), 0.0f);
    float ih = fmaxf(fminf(p.w, t.w) - fmaxf(p.y, t.y), 0.0f);
    float inter = iw * ih;
    float uni   = area_p + area_t - inter;

    float ew = fmaxf(p.z, t.z) - fminf(p.x, t.x);
    float eh = fmaxf(p.w, t.w) - fminf(p.y, t.y);
    float enclose = ew * eh;

    // 1 - giou = 2 - inter/union - union/enclose  (fast rcp: err ~1e-5 << 2.75e-2 threshold)
    return 2.0f - inter * __builtin_amdgcn_rcpf(uni)
                - uni   * __builtin_amdgcn_rcpf(enclose);
}

__global__ __launch_bounds__(GIOU_THREADS) void giou_partial_kernel(
        const v4f* __restrict__ pred,
        const v4f* __restrict__ targ,
        double* __restrict__ partials,
        int n) {
    int tid    = blockIdx.x * blockDim.x + threadIdx.x;
    int stride = gridDim.x * blockDim.x;

    float sum = 0.0f;
    int i = tid;

    // Streaming (zero-reuse) data: nontemporal loads bypass L1 allocation and
    // its outstanding-miss cap; requests queue in the deeper L2/fabric path.
    for (; i + (UNROLL - 1) * stride < n; i += UNROLL * stride) {
        v4f p[UNROLL], t[UNROLL];
        #pragma unroll
        for (int u = 0; u < UNROLL; ++u) p[u] = __builtin_nontemporal_load(&pred[i + u * stride]);
        #pragma unroll
        for (int u = 0; u < UNROLL; ++u) t[u] = __builtin_nontemporal_load(&targ[i + u * stride]);
        #pragma unroll
        for (int u = 0; u < UNROLL; ++u) sum += giou_loss(p[u], t[u]);
    }
    for (; i < n; i += stride)
        sum += giou_loss(__builtin_nontemporal_load(&pred[i]),
                         __builtin_nontemporal_load(&targ[i]));

    // wave-64 butterfly reduction
    #pragma unroll
    for (int off = 32; off > 0; off >>= 1)
        sum += __shfl_down(sum, off, 64);

    __shared__ float wave_sums[GIOU_THREADS / 64];
    int lane = threadIdx.x & 63;
    int wave = threadIdx.x >> 6;
    if (lane == 0) wave_sums[wave] = sum;
    __syncthreads();

    if (threadIdx.x == 0) {
        double b = 0.0;
        #pragma unroll
        for (int w = 0; w < GIOU_THREADS / 64; ++w) b += (double)wave_sums[w];
        partials[blockIdx.x] = b;   // every block writes unconditionally -> no memset needed
    }
}

__global__ __launch_bounds__(GIOU_THREADS) void giou_final_kernel(
        const double* __restrict__ partials,
        float* __restrict__ out,
        int nblocks, int n) {
    double s = 0.0;
    for (int i = threadIdx.x; i < nblocks; i += blockDim.x)
        s += partials[i];

    #pragma unroll
    for (int off = 32; off > 0; off >>= 1)
        s += __shfl_down(s, off, 64);

    __shared__ double wave_sums[GIOU_THREADS / 64];
    int lane = threadIdx.x & 63;
    int wave = threadIdx.x >> 6;
    if (lane == 0) wave_sums[wave] = s;
    __syncthreads();

    if (threadIdx.x == 0) {
        double tot = 0.0;
        #pragma unroll
        for (int w = 0; w < GIOU_THREADS / 64; ++w) tot += wave_sums[w];
        out[0] = (float)(tot / (double)n);
    }
}

extern "C" void kernel_launch(void* const* d_in, const int* in_sizes, int n_in,
                              void* d_out, int out_size, void* d_ws, size_t ws_size,
                              hipStream_t stream) {
    const v4f* pred = (const v4f*)d_in[0];
    const v4f* targ = (const v4f*)d_in[1];
    float* out = (float*)d_out;
    double* partials = (double*)d_ws;   // GIOU_GRID doubles = 32 KB

    int n = in_sizes[0] / 4;            // number of boxes (flat count is n*4)

    giou_partial_kernel<<<GIOU_GRID, GIOU_THREADS, 0, stream>>>(pred, targ, partials, n);
    giou_final_kernel<<<1, GIOU_THREADS, 0, stream>>>(partials, out, GIOU_GRID, n);
}

// Round 5
// 246.239 us; speedup vs baseline: 1.1069x; 1.0089x over previous
//
#include <hip/hip_runtime.h>

#define GIOU_GRID    1024
#define GIOU_THREADS 256
#define UNROLL       4

typedef float v4f __attribute__((ext_vector_type(4)));

__device__ __forceinline__ float giou_loss(v4f p, v4f t) {
    float area_p = (p.z - p.x) * (p.w - p.y);
    float area_t = (t.z - t.x) * (t.w - t.y);

    float iw = fmaxf(fminf(p.z, t.z) - fmaxf(p.x, t.x), 0.0f);
    float ih = fmaxf(fminf(p.w, t.w) - fmaxf(p.y, t.y), 0.0f);
    float inter = iw * ih;
    float uni   = area_p + area_t - inter;

    float ew = fmaxf(p.z, t.z) - fminf(p.x, t.x);
    float eh = fmaxf(p.w, t.w) - fminf(p.y, t.y);
    float enclose = ew * eh;

    // 1 - giou = 2 - inter/union - union/enclose  (fast rcp: err ~1e-5 << 2.75e-2 threshold)
    return 2.0f - inter * __builtin_amdgcn_rcpf(uni)
                - uni   * __builtin_amdgcn_rcpf(enclose);
}

__global__ __launch_bounds__(GIOU_THREADS) void giou_partial_kernel(
        const v4f* __restrict__ pred,
        const v4f* __restrict__ targ,
        double* __restrict__ partials,
        int n) {
    int tid    = blockIdx.x * blockDim.x + threadIdx.x;
    int stride = gridDim.x * blockDim.x;   // 262144 threads -> ~30.5 elems/thread

    float sum = 0.0f;
    int i = tid;

    // Main loop (~92% of traffic): 8 nontemporal dwordx4 loads in flight
    // before any compute. nt bypasses L1 allocation (and its outstanding-miss
    // cap) -- this is what broke the 2.6 TB/s plateau in R4.
    for (; i + (UNROLL - 1) * stride < n; i += UNROLL * stride) {
        v4f p[UNROLL], t[UNROLL];
        #pragma unroll
        for (int u = 0; u < UNROLL; ++u) p[u] = __builtin_nontemporal_load(&pred[i + u * stride]);
        #pragma unroll
        for (int u = 0; u < UNROLL; ++u) t[u] = __builtin_nontemporal_load(&targ[i + u * stride]);
        #pragma unroll
        for (int u = 0; u < UNROLL; ++u) sum += giou_loss(p[u], t[u]);
    }
    // 2-wide tail step (4 loads in flight)
    for (; i + stride < n; i += 2 * stride) {
        v4f p0 = __builtin_nontemporal_load(&pred[i]);
        v4f p1 = __builtin_nontemporal_load(&pred[i + stride]);
        v4f t0 = __builtin_nontemporal_load(&targ[i]);
        v4f t1 = __builtin_nontemporal_load(&targ[i + stride]);
        sum += giou_loss(p0, t0);
        sum += giou_loss(p1, t1);
    }
    // final scalar tail
    for (; i < n; i += stride)
        sum += giou_loss(__builtin_nontemporal_load(&pred[i]),
                         __builtin_nontemporal_load(&targ[i]));

    // wave-64 butterfly reduction
    #pragma unroll
    for (int off = 32; off > 0; off >>= 1)
        sum += __shfl_down(sum, off, 64);

    __shared__ float wave_sums[GIOU_THREADS / 64];
    int lane = threadIdx.x & 63;
    int wave = threadIdx.x >> 6;
    if (lane == 0) wave_sums[wave] = sum;
    __syncthreads();

    if (threadIdx.x == 0) {
        double b = 0.0;
        #pragma unroll
        for (int w = 0; w < GIOU_THREADS / 64; ++w) b += (double)wave_sums[w];
        partials[blockIdx.x] = b;   // every block writes unconditionally -> no memset needed
    }
}

__global__ __launch_bounds__(GIOU_THREADS) void giou_final_kernel(
        const double* __restrict__ partials,
        float* __restrict__ out,
        int nblocks, int n) {
    double s = 0.0;
    for (int i = threadIdx.x; i < nblocks; i += blockDim.x)
        s += partials[i];

    #pragma unroll
    for (int off = 32; off > 0; off >>= 1)
        s += __shfl_down(s, off, 64);

    __shared__ double wave_sums[GIOU_THREADS / 64];
    int lane = threadIdx.x & 63;
    int wave = threadIdx.x >> 6;
    if (lane == 0) wave_sums[wave] = s;
    __syncthreads();

    if (threadIdx.x == 0) {
        double tot = 0.0;
        #pragma unroll
        for (int w = 0; w < GIOU_THREADS / 64; ++w) tot += wave_sums[w];
        out[0] = (float)(tot / (double)n);
    }
}

extern "C" void kernel_launch(void* const* d_in, const int* in_sizes, int n_in,
                              void* d_out, int out_size, void* d_ws, size_t ws_size,
                              hipStream_t stream) {
    const v4f* pred = (const v4f*)d_in[0];
    const v4f* targ = (const v4f*)d_in[1];
    float* out = (float*)d_out;
    double* partials = (double*)d_ws;   // GIOU_GRID doubles = 8 KB

    int n = in_sizes[0] / 4;            // number of boxes (flat count is n*4)

    giou_partial_kernel<<<GIOU_GRID, GIOU_THREADS, 0, stream>>>(pred, targ, partials, n);
    giou_final_kernel<<<1, GIOU_THREADS, 0, stream>>>(partials, out, GIOU_GRID, n);
}